// Round 2
// baseline (337.025 us; speedup 1.0000x reference)
//
#include <hip/hip_runtime.h>
#include <hip/hip_bf16.h>
#include <stdint.h>

typedef unsigned short u16;
typedef unsigned int u32;

typedef __attribute__((ext_vector_type(8))) __bf16 bf16x8;
typedef __attribute__((ext_vector_type(4))) float f32x4;
typedef __attribute__((ext_vector_type(8))) u16 u16x8;

#define DIM 1024
#define SEQ 4096
#define NTOK 8192   // b*n
#define NBH 16      // b*h

static __device__ __forceinline__ u16 f2bf(float f) {
    union { float f; u32 u; } c; c.f = f;
    u32 u = c.u;
    return (u16)((u + 0x7FFF + ((u >> 16) & 1)) >> 16);
}
static __device__ __forceinline__ f32x4 mfma_bf16(bf16x8 a, bf16x8 b, f32x4 c) {
    return __builtin_amdgcn_mfma_f32_16x16x32_bf16(a, b, c, 0, 0, 0);
}

// ---------------- LayerNorm: one block per token row (fp32 in, bf16 out) ----
__global__ __launch_bounds__(256) void ln_kernel(const float* __restrict__ x,
                                                 const float* __restrict__ g,
                                                 const float* __restrict__ bta,
                                                 u16* __restrict__ xn) {
    int row = blockIdx.x;
    int tid = threadIdx.x;
    float4 v = ((const float4*)(x + (size_t)row * DIM))[tid];
    float f[4] = {v.x, v.y, v.z, v.w};
    float s = 0.f, s2 = 0.f;
#pragma unroll
    for (int i = 0; i < 4; i++) { s += f[i]; s2 += f[i] * f[i]; }
#pragma unroll
    for (int m = 1; m < 64; m <<= 1) { s += __shfl_xor(s, m); s2 += __shfl_xor(s2, m); }
    __shared__ float red[8];
    int w = tid >> 6;
    if ((tid & 63) == 0) { red[w * 2] = s; red[w * 2 + 1] = s2; }
    __syncthreads();
    s  = red[0] + red[2] + red[4] + red[6];
    s2 = red[1] + red[3] + red[5] + red[7];
    float mu = s * (1.f / DIM);
    float var = s2 * (1.f / DIM) - mu * mu;
    float rstd = rsqrtf(var + 1e-5f);
    u16 o[4];
#pragma unroll
    for (int i = 0; i < 4; i++) {
        int c = tid * 4 + i;
        o[i] = f2bf((f[i] - mu) * rstd * g[c] + bta[c]);
    }
    *(uint64_t*)(xn + (size_t)row * DIM + tid * 4) = *(uint64_t*)o;
}

// ---------------- transpose src[R][C] fp32 -> dst[C][R] bf16 ----------------
__global__ __launch_bounds__(256) void transpose_kernel(const float* __restrict__ src,
                                                        u16* __restrict__ dst,
                                                        int R, int C) {
    __shared__ float t[32][33];
    int lx = threadIdx.x & 31, ly = threadIdx.x >> 5;
    int c = blockIdx.x * 32 + lx;
#pragma unroll
    for (int i = 0; i < 32; i += 8)
        t[ly + i][lx] = src[(size_t)(blockIdx.y * 32 + ly + i) * C + c];
    __syncthreads();
    int rr = blockIdx.y * 32 + lx;
#pragma unroll
    for (int i = 0; i < 32; i += 8)
        dst[(size_t)(blockIdx.x * 32 + ly + i) * R + rr] = f2bf(t[lx][ly + i]);
}

// ---------------- 128x128 MFMA GEMM core ----------------
// A: [M][K] row-major bf16, B: [N][K] row-major bf16 (i.e. B^T of math B)
// Block = 256 thr = 4 waves in 2x2; each wave 64x64 via 4x4 16x16x32 MFMAs.
#define LDSTR 40  // 32 + 8 pad (80 B rows, 16B-aligned, 2-way bank alias = free)

template <int K>
static __device__ __forceinline__ void gemm_core(const u16* __restrict__ A,
                                                 const u16* __restrict__ B,
                                                 int rowBase, int colBase,
                                                 u16* A_lds, u16* B_lds,
                                                 f32x4 acc[4][4]) {
    int tid = threadIdx.x;
    int lane = tid & 63;
    int w = tid >> 6;
    int wm = w >> 1, wn = w & 1;
#pragma unroll
    for (int mt = 0; mt < 4; mt++)
#pragma unroll
        for (int nt = 0; nt < 4; nt++) acc[mt][nt] = (f32x4){0.f, 0.f, 0.f, 0.f};

    for (int k0 = 0; k0 < K; k0 += 32) {
        __syncthreads();
#pragma unroll
        for (int i = 0; i < 2; i++) {
            int c = tid + 256 * i;
            int r = c >> 2;
            int kc = (c & 3) * 8;
            *(u16x8*)(A_lds + r * LDSTR + kc) =
                *(const u16x8*)(A + (size_t)(rowBase + r) * K + k0 + kc);
            *(u16x8*)(B_lds + r * LDSTR + kc) =
                *(const u16x8*)(B + (size_t)(colBase + r) * K + k0 + kc);
        }
        __syncthreads();
        bf16x8 a[4], b[4];
#pragma unroll
        for (int mt = 0; mt < 4; mt++)
            a[mt] = *(const bf16x8*)(A_lds + (wm * 64 + mt * 16 + (lane & 15)) * LDSTR + (lane >> 4) * 8);
#pragma unroll
        for (int nt = 0; nt < 4; nt++)
            b[nt] = *(const bf16x8*)(B_lds + (wn * 64 + nt * 16 + (lane & 15)) * LDSTR + (lane >> 4) * 8);
#pragma unroll
        for (int mt = 0; mt < 4; mt++)
#pragma unroll
            for (int nt = 0; nt < 4; nt++)
                acc[mt][nt] = mfma_bf16(a[mt], b[nt], acc[mt][nt]);
    }
}

// QKV GEMM: C[8192][1536] scattered into q/k/v [bh][n][64] (bf16)
__global__ __launch_bounds__(256) void gemm_qkv_kernel(const u16* __restrict__ xn,
                                                       const u16* __restrict__ wT,
                                                       u16* __restrict__ qb,
                                                       u16* __restrict__ kb,
                                                       u16* __restrict__ vb) {
    __shared__ u16 A_lds[128 * LDSTR];
    __shared__ u16 B_lds[128 * LDSTR];
    f32x4 acc[4][4];
    gemm_core<1024>(xn, wT, blockIdx.x * 128, blockIdx.y * 128, A_lds, B_lds, acc);
    int lane = threadIdx.x & 63;
    int w = threadIdx.x >> 6;
    int wm = w >> 1, wn = w & 1;
#pragma unroll
    for (int mt = 0; mt < 4; mt++) {
#pragma unroll
        for (int nt = 0; nt < 4; nt++) {
#pragma unroll
            for (int r = 0; r < 4; r++) {
                int m = blockIdx.x * 128 + wm * 64 + mt * 16 + (lane >> 4) * 4 + r;
                int n = blockIdx.y * 128 + wn * 64 + nt * 16 + (lane & 15);
                int piece = n >> 9;
                int c = n & 511;
                int h = c >> 6;
                int d = c & 63;
                int bi = m >> 12;
                int nn = m & 4095;
                u16* dst = piece == 0 ? qb : (piece == 1 ? kb : vb);
                dst[((size_t)((bi * 8 + h) * SEQ + nn) << 6) + d] = f2bf(acc[mt][nt][r]);
            }
        }
    }
}

// Out projection GEMM: attn_out[8192][512] bf16 @ w_outT -> d_out[8192][1024] fp32
__global__ __launch_bounds__(256) void gemm_out_kernel(const u16* __restrict__ aout,
                                                       const u16* __restrict__ wT,
                                                       float* __restrict__ out) {
    __shared__ u16 A_lds[128 * LDSTR];
    __shared__ u16 B_lds[128 * LDSTR];
    f32x4 acc[4][4];
    gemm_core<512>(aout, wT, blockIdx.x * 128, blockIdx.y * 128, A_lds, B_lds, acc);
    int lane = threadIdx.x & 63;
    int w = threadIdx.x >> 6;
    int wm = w >> 1, wn = w & 1;
#pragma unroll
    for (int mt = 0; mt < 4; mt++) {
#pragma unroll
        for (int nt = 0; nt < 4; nt++) {
#pragma unroll
            for (int r = 0; r < 4; r++) {
                int m = blockIdx.x * 128 + wm * 64 + mt * 16 + (lane >> 4) * 4 + r;
                int n = blockIdx.y * 128 + wn * 64 + nt * 16 + (lane & 15);
                out[(size_t)m * DIM + n] = acc[mt][nt][r];
            }
        }
    }
}

// ---------------- causal flash attention ----------------
// grid 1024: bh = flat&15, qtile = 63 - (flat>>4) (heaviest tiles dispatched first)
// 4 waves; wave w owns queries [w*16, w*16+16) of the 64-query tile.
#define ASTR 72  // 64 + 8 pad

__global__ __launch_bounds__(256) void attn_kernel(const u16* __restrict__ qb,
                                                   const u16* __restrict__ kb,
                                                   const u16* __restrict__ vb,
                                                   u16* __restrict__ aout) {
    __shared__ u16 Q_lds[64 * ASTR];
    __shared__ u16 K_lds[64 * ASTR];
    __shared__ u16 VT_lds[64 * ASTR];
    __shared__ u16 P_lds[4 * 16 * ASTR];

    int flat = blockIdx.x;
    int bh = flat & 15;
    int qt = 63 - (flat >> 4);
    int tid = threadIdx.x;
    int lane = tid & 63;
    int w = tid >> 6;

    const u16* Qp = qb + ((size_t)bh * SEQ + qt * 64) * 64;
    const u16* Kp0 = kb + (size_t)bh * SEQ * 64;
    const u16* Vp0 = vb + (size_t)bh * SEQ * 64;

#pragma unroll
    for (int i = 0; i < 2; i++) {
        int c = tid + 256 * i;
        int r = c >> 3;
        int kc = (c & 7) * 8;
        *(u16x8*)(Q_lds + r * ASTR + kc) = *(const u16x8*)(Qp + r * 64 + kc);
    }

    float m_old[4], l_run[4];
    f32x4 Oacc[4];
#pragma unroll
    for (int r = 0; r < 4; r++) { m_old[r] = -1.0e30f; l_run[r] = 0.f; }
#pragma unroll
    for (int vt = 0; vt < 4; vt++) Oacc[vt] = (f32x4){0.f, 0.f, 0.f, 0.f};

    const float scale = 0.125f;
    u16* Pw = P_lds + w * 16 * ASTR;

    for (int kt = 0; kt <= qt; kt++) {
        __syncthreads();
        const u16* Kp = Kp0 + (size_t)kt * 64 * 64;
        const u16* Vp = Vp0 + (size_t)kt * 64 * 64;
#pragma unroll
        for (int i = 0; i < 2; i++) {
            int c = tid + 256 * i;
            int r = c >> 3;
            int kc = (c & 7) * 8;
            *(u16x8*)(K_lds + r * ASTR + kc) = *(const u16x8*)(Kp + r * 64 + kc);
            u16x8 vv = *(const u16x8*)(Vp + r * 64 + kc);
#pragma unroll
            for (int j = 0; j < 8; j++) VT_lds[(kc + j) * ASTR + r] = vv[j];
        }
        __syncthreads();

        // S = Q K^T for this wave's 16 queries x 64 keys
        bf16x8 aQ0 = *(const bf16x8*)(Q_lds + (w * 16 + (lane & 15)) * ASTR + (lane >> 4) * 8);
        bf16x8 aQ1 = *(const bf16x8*)(Q_lds + (w * 16 + (lane & 15)) * ASTR + 32 + (lane >> 4) * 8);
        f32x4 s[4];
#pragma unroll
        for (int nt = 0; nt < 4; nt++) {
            bf16x8 b0 = *(const bf16x8*)(K_lds + (nt * 16 + (lane & 15)) * ASTR + (lane >> 4) * 8);
            bf16x8 b1 = *(const bf16x8*)(K_lds + (nt * 16 + (lane & 15)) * ASTR + 32 + (lane >> 4) * 8);
            f32x4 z = (f32x4){0.f, 0.f, 0.f, 0.f};
            z = mfma_bf16(aQ0, b0, z);
            z = mfma_bf16(aQ1, b1, z);
            s[nt] = z;
        }

        bool diag = (kt == qt);
        float p[4][4];
        float mt_r[4];
#pragma unroll
        for (int r = 0; r < 4; r++) {
            float mx = -1.0e30f;
#pragma unroll
            for (int nt = 0; nt < 4; nt++) {
                float sv = s[nt][r] * scale;
                if (diag) {
                    int kg = nt * 16 + (lane & 15);
                    int qg = w * 16 + (lane >> 4) * 4 + r;
                    if (kg > qg) sv = -1.0e30f;
                }
                p[nt][r] = sv;
                mx = fmaxf(mx, sv);
            }
            mt_r[r] = mx;
        }
#pragma unroll
        for (int msk = 1; msk < 16; msk <<= 1)
#pragma unroll
            for (int r = 0; r < 4; r++) mt_r[r] = fmaxf(mt_r[r], __shfl_xor(mt_r[r], msk));

        float alpha[4], rowsum[4];
#pragma unroll
        for (int r = 0; r < 4; r++) {
            float mn = fmaxf(m_old[r], mt_r[r]);
            alpha[r] = __expf(m_old[r] - mn);
            m_old[r] = mn;
            float rs = 0.f;
#pragma unroll
            for (int nt = 0; nt < 4; nt++) {
                float pv = __expf(p[nt][r] - mn);
                p[nt][r] = pv;
                rs += pv;
            }
            rowsum[r] = rs;
        }
#pragma unroll
        for (int msk = 1; msk < 16; msk <<= 1)
#pragma unroll
            for (int r = 0; r < 4; r++) rowsum[r] += __shfl_xor(rowsum[r], msk);
#pragma unroll
        for (int r = 0; r < 4; r++) l_run[r] = l_run[r] * alpha[r] + rowsum[r];
#pragma unroll
        for (int vt = 0; vt < 4; vt++)
#pragma unroll
            for (int r = 0; r < 4; r++) Oacc[vt][r] *= alpha[r];

        // P (C/D layout) -> LDS -> A-operand layout
#pragma unroll
        for (int nt = 0; nt < 4; nt++)
#pragma unroll
            for (int r = 0; r < 4; r++)
                Pw[((lane >> 4) * 4 + r) * ASTR + nt * 16 + (lane & 15)] = f2bf(p[nt][r]);
        __syncthreads();

#pragma unroll
        for (int vt = 0; vt < 4; vt++) {
#pragma unroll
            for (int ks = 0; ks < 2; ks++) {
                bf16x8 aP = *(const bf16x8*)(Pw + (lane & 15) * ASTR + ks * 32 + (lane >> 4) * 8);
                bf16x8 bV = *(const bf16x8*)(VT_lds + (vt * 16 + (lane & 15)) * ASTR + ks * 32 + (lane >> 4) * 8);
                Oacc[vt] = mfma_bf16(aP, bV, Oacc[vt]);
            }
        }
    }

    int b = bh >> 3;
    int h = bh & 7;
    float inv[4];
#pragma unroll
    for (int r = 0; r < 4; r++) inv[r] = 1.f / (l_run[r] + 1e-10f);
#pragma unroll
    for (int vt = 0; vt < 4; vt++) {
#pragma unroll
        for (int r = 0; r < 4; r++) {
            int q = qt * 64 + w * 16 + (lane >> 4) * 4 + r;
            int col = h * 64 + vt * 16 + (lane & 15);
            aout[(size_t)(b * SEQ + q) * 512 + col] = f2bf(Oacc[vt][r] * inv[r]);
        }
    }
}

extern "C" void kernel_launch(void* const* d_in, const int* in_sizes, int n_in,
                              void* d_out, int out_size, void* d_ws, size_t ws_size,
                              hipStream_t stream) {
    const float* x    = (const float*)d_in[0];
    const float* g    = (const float*)d_in[1];
    const float* bta  = (const float*)d_in[2];
    const float* wqkv = (const float*)d_in[3];
    const float* wout = (const float*)d_in[4];
    float* out = (float*)d_out;

    char* ws = (char*)d_ws;
    size_t off = 0;
    auto alloc = [&](size_t bytes) {
        void* p = ws + off;
        off += (bytes + 255) & ~(size_t)255;
        return p;
    };
    u16* xn    = (u16*)alloc((size_t)NTOK * DIM * 2);
    u16* wqkvT = (u16*)alloc((size_t)1536 * 1024 * 2);
    u16* woutT = (u16*)alloc((size_t)1024 * 512 * 2);
    u16* qb    = (u16*)alloc((size_t)NBH * SEQ * 64 * 2);
    u16* kb    = (u16*)alloc((size_t)NBH * SEQ * 64 * 2);
    u16* vb    = (u16*)alloc((size_t)NBH * SEQ * 64 * 2);
    u16* aout  = (u16*)alloc((size_t)NTOK * 512 * 2);

    ln_kernel<<<NTOK, 256, 0, stream>>>(x, g, bta, xn);
    transpose_kernel<<<dim3(1536 / 32, 1024 / 32), 256, 0, stream>>>(wqkv, wqkvT, 1024, 1536);
    transpose_kernel<<<dim3(1024 / 32, 512 / 32), 256, 0, stream>>>(wout, woutT, 512, 1024);
    gemm_qkv_kernel<<<dim3(64, 12), 256, 0, stream>>>(xn, wqkvT, qb, kb, vb);
    attn_kernel<<<1024, 256, 0, stream>>>(qb, kb, vb, aout);
    gemm_out_kernel<<<dim3(64, 8), 256, 0, stream>>>(aout, woutT, out);
}

// Round 4
// 280.103 us; speedup vs baseline: 1.2032x; 1.2032x over previous
//
#include <hip/hip_runtime.h>
#include <hip/hip_bf16.h>
#include <stdint.h>

typedef unsigned short u16;
typedef unsigned int u32;

typedef __attribute__((ext_vector_type(8))) __bf16 bf16x8;
typedef __attribute__((ext_vector_type(4))) float f32x4;
typedef __attribute__((ext_vector_type(8))) u16 u16x8;

#define DIM 1024
#define SEQ 4096
#define NTOK 8192   // b*n
#define NBH 16      // b*h

static __device__ __forceinline__ u16 f2bf(float f) {
    union { float f; u32 u; } c; c.f = f;
    u32 u = c.u;
    return (u16)((u + 0x7FFF + ((u >> 16) & 1)) >> 16);
}
static __device__ __forceinline__ u16 cvt_bf16(float f) {
    union { __bf16 b; u16 u; } c; c.b = (__bf16)f;  // RNE
    return c.u;
}
static __device__ __forceinline__ f32x4 mfma_bf16(bf16x8 a, bf16x8 b, f32x4 c) {
    return __builtin_amdgcn_mfma_f32_16x16x32_bf16(a, b, c, 0, 0, 0);
}

typedef const __attribute__((address_space(1))) unsigned int* gptr_t;
typedef __attribute__((address_space(3))) unsigned int* lptr_t;

// ---------------- LayerNorm: one block per token row (fp32 in, bf16 out) ----
__global__ __launch_bounds__(256) void ln_kernel(const float* __restrict__ x,
                                                 const float* __restrict__ g,
                                                 const float* __restrict__ bta,
                                                 u16* __restrict__ xn) {
    int row = blockIdx.x;
    int tid = threadIdx.x;
    float4 v = ((const float4*)(x + (size_t)row * DIM))[tid];
    float f[4] = {v.x, v.y, v.z, v.w};
    float s = 0.f, s2 = 0.f;
#pragma unroll
    for (int i = 0; i < 4; i++) { s += f[i]; s2 += f[i] * f[i]; }
#pragma unroll
    for (int m = 1; m < 64; m <<= 1) { s += __shfl_xor(s, m); s2 += __shfl_xor(s2, m); }
    __shared__ float red[8];
    int w = tid >> 6;
    if ((tid & 63) == 0) { red[w * 2] = s; red[w * 2 + 1] = s2; }
    __syncthreads();
    s  = red[0] + red[2] + red[4] + red[6];
    s2 = red[1] + red[3] + red[5] + red[7];
    float mu = s * (1.f / DIM);
    float var = s2 * (1.f / DIM) - mu * mu;
    float rstd = rsqrtf(var + 1e-5f);
    u16 o[4];
#pragma unroll
    for (int i = 0; i < 4; i++) {
        int c = tid * 4 + i;
        o[i] = f2bf((f[i] - mu) * rstd * g[c] + bta[c]);
    }
    *(uint64_t*)(xn + (size_t)row * DIM + tid * 4) = *(uint64_t*)o;
}

// ---------------- transpose src[R][C] fp32 -> dst[C][R] bf16 ----------------
__global__ __launch_bounds__(256) void transpose_kernel(const float* __restrict__ src,
                                                        u16* __restrict__ dst,
                                                        int R, int C) {
    __shared__ float t[32][33];
    int lx = threadIdx.x & 31, ly = threadIdx.x >> 5;
    int c = blockIdx.x * 32 + lx;
#pragma unroll
    for (int i = 0; i < 32; i += 8)
        t[ly + i][lx] = src[(size_t)(blockIdx.y * 32 + ly + i) * C + c];
    __syncthreads();
    int rr = blockIdx.y * 32 + lx;
#pragma unroll
    for (int i = 0; i < 32; i += 8)
        dst[(size_t)(blockIdx.x * 32 + ly + i) * R + rr] = f2bf(t[lx][ly + i]);
}

// ---------------- 128x128 MFMA GEMM core (m97-style global_load_lds) -------
// A: [M][K] row-major bf16, B: [N][K] row-major bf16 (B^T of math B).
// LDS tiles unpadded [128][32] so global_load_lds (wave-uniform base + lane*16)
// lands correctly: chunk c = i*256+tid -> lds byte off c*16 = i*4096 + w*1024 + lane*16.
template <int K>
static __device__ __forceinline__ void gemm_core(const u16* __restrict__ A,
                                                 const u16* __restrict__ B,
                                                 int rowBase, int colBase,
                                                 u16* A_lds, u16* B_lds,
                                                 f32x4 acc[4][4]) {
    int tid = threadIdx.x;
    int lane = tid & 63;
    int l15 = lane & 15, q4 = lane >> 4;
    int w = tid >> 6;
    int wm = w >> 1, wn = w & 1;
#pragma unroll
    for (int mt = 0; mt < 4; mt++)
#pragma unroll
        for (int nt = 0; nt < 4; nt++) acc[mt][nt] = (f32x4){0.f, 0.f, 0.f, 0.f};

    char* Ab = (char*)A_lds;
    char* Bb = (char*)B_lds;

    for (int k0 = 0; k0 < K; k0 += 32) {
        __syncthreads();
#pragma unroll
        for (int i = 0; i < 2; i++) {
            int c = i * 256 + tid;
            int r = c >> 2;
            int piece = (c & 3) * 8;
            const u16* gA = A + (size_t)(rowBase + r) * K + k0 + piece;
            const u16* gB = B + (size_t)(colBase + r) * K + k0 + piece;
            unsigned ldsOff = (unsigned)(i * 4096 + w * 1024);  // wave-uniform
            __builtin_amdgcn_global_load_lds((gptr_t)gA, (lptr_t)(Ab + ldsOff), 16, 0, 0);
            __builtin_amdgcn_global_load_lds((gptr_t)gB, (lptr_t)(Bb + ldsOff), 16, 0, 0);
        }
        __syncthreads();
        bf16x8 a[4], b[4];
#pragma unroll
        for (int mt = 0; mt < 4; mt++)
            a[mt] = *(const bf16x8*)(A_lds + (wm * 64 + mt * 16 + l15) * 32 + q4 * 8);
#pragma unroll
        for (int nt = 0; nt < 4; nt++)
            b[nt] = *(const bf16x8*)(B_lds + (wn * 64 + nt * 16 + l15) * 32 + q4 * 8);
#pragma unroll
        for (int mt = 0; mt < 4; mt++)
#pragma unroll
            for (int nt = 0; nt < 4; nt++)
                acc[mt][nt] = mfma_bf16(a[mt], b[nt], acc[mt][nt]);
    }
}

// QKV GEMM: C[8192][1536] scattered into q/k [bh][n][64], v TRANSPOSED [bh][d][n]
__global__ __launch_bounds__(256) void gemm_qkv_kernel(const u16* __restrict__ xn,
                                                       const u16* __restrict__ wT,
                                                       u16* __restrict__ qb,
                                                       u16* __restrict__ kb,
                                                       u16* __restrict__ vbT) {
    __shared__ u16 A_lds[128 * 32];
    __shared__ u16 B_lds[128 * 32];
    f32x4 acc[4][4];
    gemm_core<1024>(xn, wT, blockIdx.x * 128, blockIdx.y * 128, A_lds, B_lds, acc);
    int lane = threadIdx.x & 63;
    int w = threadIdx.x >> 6;
    int wm = w >> 1, wn = w & 1;
#pragma unroll
    for (int mt = 0; mt < 4; mt++) {
#pragma unroll
        for (int nt = 0; nt < 4; nt++) {
#pragma unroll
            for (int r = 0; r < 4; r++) {
                int m = blockIdx.x * 128 + wm * 64 + mt * 16 + (lane >> 4) * 4 + r;
                int n = blockIdx.y * 128 + wn * 64 + nt * 16 + (lane & 15);
                int piece = n >> 9;
                int c = n & 511;
                int h = c >> 6;
                int d = c & 63;
                int bi = m >> 12;
                int nn = m & 4095;
                int bh = bi * 8 + h;
                u16 val = f2bf(acc[mt][nt][r]);
                if (piece == 0)      qb[((size_t)(bh * SEQ + nn) << 6) + d] = val;
                else if (piece == 1) kb[((size_t)(bh * SEQ + nn) << 6) + d] = val;
                else                 vbT[((size_t)(bh * 64 + d) << 12) + nn] = val;
            }
        }
    }
}

// Out projection GEMM: attn_out[8192][512] bf16 @ w_outT -> d_out[8192][1024] fp32
__global__ __launch_bounds__(256) void gemm_out_kernel(const u16* __restrict__ aout,
                                                       const u16* __restrict__ wT,
                                                       float* __restrict__ out) {
    __shared__ u16 A_lds[128 * 32];
    __shared__ u16 B_lds[128 * 32];
    f32x4 acc[4][4];
    gemm_core<512>(aout, wT, blockIdx.x * 128, blockIdx.y * 128, A_lds, B_lds, acc);
    int lane = threadIdx.x & 63;
    int w = threadIdx.x >> 6;
    int wm = w >> 1, wn = w & 1;
#pragma unroll
    for (int mt = 0; mt < 4; mt++) {
#pragma unroll
        for (int nt = 0; nt < 4; nt++) {
#pragma unroll
            for (int r = 0; r < 4; r++) {
                int m = blockIdx.x * 128 + wm * 64 + mt * 16 + (lane >> 4) * 4 + r;
                int n = blockIdx.y * 128 + wn * 64 + nt * 16 + (lane & 15);
                out[(size_t)m * DIM + n] = acc[mt][nt][r];
            }
        }
    }
}

// ---------------- causal flash attention (no-max softmax) ----------------
// grid 1024. qt chosen so any stride-256 resident set has constant work-sum:
// k6 = f>>4, a = k6>>4, b = k6&15, qt = 16a + (a odd ? 15-b : b).
// 4 waves; wave w owns queries [w*16, w*16+16). Q_lds and P_lds share storage.
#define ASTR 72  // 64 + 8 pad (144 B rows -> 4-bank row shift, 2-way alias = free)

__global__ __launch_bounds__(256) void attn_kernel(const u16* __restrict__ qb,
                                                   const u16* __restrict__ kb,
                                                   const u16* __restrict__ vbT,
                                                   u16* __restrict__ aout) {
    __shared__ u16 K_lds[64 * ASTR];
    __shared__ u16 VT_lds[64 * ASTR];
    __shared__ u16 QP_lds[64 * ASTR];  // Q tile, then per-wave P scratch

    int f = blockIdx.x;
    int bh = f & 15;
    int k6 = f >> 4;
    int a = k6 >> 4, b6 = k6 & 15;
    int qt = 16 * a + ((a & 1) ? (15 - b6) : b6);

    int tid = threadIdx.x;
    int lane = tid & 63;
    int l15 = lane & 15, q4 = lane >> 4;
    int w = tid >> 6;

    const u16* Qp  = qb + ((size_t)bh * SEQ + qt * 64) * 64;
    const u16* Kp0 = kb + (size_t)bh * SEQ * 64;
    const u16* VTp = vbT + ((size_t)bh * 64) * SEQ;

#pragma unroll
    for (int i = 0; i < 2; i++) {
        int c = tid + 256 * i;
        int r = c >> 3;
        int kc = (c & 7) * 8;
        *(u16x8*)(QP_lds + r * ASTR + kc) = *(const u16x8*)(Qp + r * 64 + kc);
    }
    __syncthreads();
    bf16x8 aQ0 = *(const bf16x8*)(QP_lds + (w * 16 + l15) * ASTR + q4 * 8);
    bf16x8 aQ1 = *(const bf16x8*)(QP_lds + (w * 16 + l15) * ASTR + 32 + q4 * 8);
    __syncthreads();  // drain all waves' Q reads before P overwrites the region

    float l_run[4] = {0.f, 0.f, 0.f, 0.f};
    f32x4 Oacc[4];
#pragma unroll
    for (int vt = 0; vt < 4; vt++) Oacc[vt] = (f32x4){0.f, 0.f, 0.f, 0.f};

    const float SC = 0.125f * 1.44269504f;  // scale * log2(e); exp2 path
    u16* Pw = QP_lds + w * 16 * ASTR;

    for (int kt = 0; kt <= qt; kt++) {
        __syncthreads();
        const u16* Kp = Kp0 + (size_t)kt * 64 * 64;
#pragma unroll
        for (int i = 0; i < 2; i++) {
            int c = tid + 256 * i;
            int r = c >> 3;
            int kc = (c & 7) * 8;
            *(u16x8*)(K_lds + r * ASTR + kc) = *(const u16x8*)(Kp + r * 64 + kc);
            // V^T staged straight from pre-transposed vbT: row r = d, cols = keys
            *(u16x8*)(VT_lds + r * ASTR + kc) = *(const u16x8*)(VTp + (size_t)r * SEQ + kt * 64 + kc);
        }
        __syncthreads();

        f32x4 s[4];
#pragma unroll
        for (int nt = 0; nt < 4; nt++) {
            bf16x8 b0 = *(const bf16x8*)(K_lds + (nt * 16 + l15) * ASTR + q4 * 8);
            bf16x8 b1 = *(const bf16x8*)(K_lds + (nt * 16 + l15) * ASTR + 32 + q4 * 8);
            f32x4 z = (f32x4){0.f, 0.f, 0.f, 0.f};
            z = mfma_bf16(aQ0, b0, z);
            z = mfma_bf16(aQ1, b1, z);
            s[nt] = z;
        }

        float p[4][4];
        float rs[4] = {0.f, 0.f, 0.f, 0.f};
        if (kt != qt) {
#pragma unroll
            for (int nt = 0; nt < 4; nt++)
#pragma unroll
                for (int r = 0; r < 4; r++) {
                    float pv = __builtin_amdgcn_exp2f(s[nt][r] * SC);
                    p[nt][r] = pv;
                    rs[r] += pv;
                }
        } else {
#pragma unroll
            for (int nt = 0; nt < 4; nt++)
#pragma unroll
                for (int r = 0; r < 4; r++) {
                    int kg = nt * 16 + l15;
                    int qg = w * 16 + q4 * 4 + r;  // FIX: w*16 term restored (round-3 bug)
                    float pv = (kg <= qg) ? __builtin_amdgcn_exp2f(s[nt][r] * SC) : 0.f;
                    p[nt][r] = pv;
                    rs[r] += pv;
                }
        }
#pragma unroll
        for (int msk = 1; msk < 16; msk <<= 1)
#pragma unroll
            for (int r = 0; r < 4; r++) rs[r] += __shfl_xor(rs[r], msk);
#pragma unroll
        for (int r = 0; r < 4; r++) l_run[r] += rs[r];

        // P (C/D layout) -> wave-private LDS -> A-operand layout (no barrier needed)
#pragma unroll
        for (int nt = 0; nt < 4; nt++)
#pragma unroll
            for (int r = 0; r < 4; r++)
                Pw[(q4 * 4 + r) * ASTR + nt * 16 + l15] = cvt_bf16(p[nt][r]);

#pragma unroll
        for (int vt = 0; vt < 4; vt++) {
#pragma unroll
            for (int ks = 0; ks < 2; ks++) {
                bf16x8 aP = *(const bf16x8*)(Pw + l15 * ASTR + ks * 32 + q4 * 8);
                bf16x8 bV = *(const bf16x8*)(VT_lds + (vt * 16 + l15) * ASTR + ks * 32 + q4 * 8);
                Oacc[vt] = mfma_bf16(aP, bV, Oacc[vt]);
            }
        }
    }

    int b = bh >> 3;
    int h = bh & 7;
    float inv[4];
#pragma unroll
    for (int r = 0; r < 4; r++) inv[r] = 1.f / (l_run[r] + 1e-10f);
#pragma unroll
    for (int vt = 0; vt < 4; vt++) {
#pragma unroll
        for (int r = 0; r < 4; r++) {
            int q = qt * 64 + w * 16 + q4 * 4 + r;
            int col = h * 64 + vt * 16 + l15;
            aout[(size_t)(b * SEQ + q) * 512 + col] = f2bf(Oacc[vt][r] * inv[r]);
        }
    }
}

extern "C" void kernel_launch(void* const* d_in, const int* in_sizes, int n_in,
                              void* d_out, int out_size, void* d_ws, size_t ws_size,
                              hipStream_t stream) {
    const float* x    = (const float*)d_in[0];
    const float* g    = (const float*)d_in[1];
    const float* bta  = (const float*)d_in[2];
    const float* wqkv = (const float*)d_in[3];
    const float* wout = (const float*)d_in[4];
    float* out = (float*)d_out;

    char* ws = (char*)d_ws;
    size_t off = 0;
    auto alloc = [&](size_t bytes) {
        void* p = ws + off;
        off += (bytes + 255) & ~(size_t)255;
        return p;
    };
    u16* xn    = (u16*)alloc((size_t)NTOK * DIM * 2);
    u16* wqkvT = (u16*)alloc((size_t)1536 * 1024 * 2);
    u16* woutT = (u16*)alloc((size_t)1024 * 512 * 2);
    u16* qb    = (u16*)alloc((size_t)NBH * SEQ * 64 * 2);
    u16* kb    = (u16*)alloc((size_t)NBH * SEQ * 64 * 2);
    u16* vbT   = (u16*)alloc((size_t)NBH * SEQ * 64 * 2);
    u16* aout  = (u16*)alloc((size_t)NTOK * 512 * 2);

    ln_kernel<<<NTOK, 256, 0, stream>>>(x, g, bta, xn);
    transpose_kernel<<<dim3(1536 / 32, 1024 / 32), 256, 0, stream>>>(wqkv, wqkvT, 1024, 1536);
    transpose_kernel<<<dim3(1024 / 32, 512 / 32), 256, 0, stream>>>(wout, woutT, 512, 1024);
    gemm_qkv_kernel<<<dim3(64, 12), 256, 0, stream>>>(xn, wqkvT, qb, kb, vbT);
    attn_kernel<<<1024, 256, 0, stream>>>(qb, kb, vbT, aout);
    gemm_out_kernel<<<dim3(64, 8), 256, 0, stream>>>(aout, woutT, out);
}

// Round 6
// 245.787 us; speedup vs baseline: 1.3712x; 1.1396x over previous
//
#include <hip/hip_runtime.h>
#include <hip/hip_bf16.h>
#include <stdint.h>

typedef unsigned short u16;
typedef unsigned int u32;

typedef __attribute__((ext_vector_type(8))) __bf16 bf16x8;
typedef __attribute__((ext_vector_type(4))) float f32x4;
typedef __attribute__((ext_vector_type(8))) u16 u16x8;

#define DIM 1024
#define SEQ 4096
#define NTOK 8192   // b*n
#define NBH 16      // b*h
#define NSLOT 96    // per-head split-K slots: qt<32 -> 1 chunk, qt>=32 -> 2 chunks (32 k-tiles each)

static __device__ __forceinline__ float bf2f(u16 u) {
    union { u32 u; float f; } c; c.u = ((u32)u) << 16; return c.f;
}
static __device__ __forceinline__ u16 f2bf(float f) {
    union { float f; u32 u; } c; c.f = f;
    u32 u = c.u;
    return (u16)((u + 0x7FFF + ((u >> 16) & 1)) >> 16);
}
static __device__ __forceinline__ u16 cvt_bf16(float f) {
    union { __bf16 b; u16 u; } c; c.b = (__bf16)f;  // RNE
    return c.u;
}
static __device__ __forceinline__ f32x4 mfma_bf16(bf16x8 a, bf16x8 b, f32x4 c) {
    return __builtin_amdgcn_mfma_f32_16x16x32_bf16(a, b, c, 0, 0, 0);
}

typedef const __attribute__((address_space(1))) unsigned int* gptr_t;
typedef __attribute__((address_space(3))) unsigned int* lptr_t;

// ---------------- LayerNorm: one block per token row (fp32 in, bf16 out) ----
__global__ __launch_bounds__(256) void ln_kernel(const float* __restrict__ x,
                                                 const float* __restrict__ g,
                                                 const float* __restrict__ bta,
                                                 u16* __restrict__ xn) {
    int row = blockIdx.x;
    int tid = threadIdx.x;
    float4 v = ((const float4*)(x + (size_t)row * DIM))[tid];
    float f[4] = {v.x, v.y, v.z, v.w};
    float s = 0.f, s2 = 0.f;
#pragma unroll
    for (int i = 0; i < 4; i++) { s += f[i]; s2 += f[i] * f[i]; }
#pragma unroll
    for (int m = 1; m < 64; m <<= 1) { s += __shfl_xor(s, m); s2 += __shfl_xor(s2, m); }
    __shared__ float red[8];
    int w = tid >> 6;
    if ((tid & 63) == 0) { red[w * 2] = s; red[w * 2 + 1] = s2; }
    __syncthreads();
    s  = red[0] + red[2] + red[4] + red[6];
    s2 = red[1] + red[3] + red[5] + red[7];
    float mu = s * (1.f / DIM);
    float var = s2 * (1.f / DIM) - mu * mu;
    float rstd = rsqrtf(var + 1e-5f);
    u16 o[4];
#pragma unroll
    for (int i = 0; i < 4; i++) {
        int c = tid * 4 + i;
        o[i] = f2bf((f[i] - mu) * rstd * g[c] + bta[c]);
    }
    *(uint64_t*)(xn + (size_t)row * DIM + tid * 4) = *(uint64_t*)o;
}

// ---------------- transpose src[R][C] fp32 -> dst[C][R] bf16 ----------------
__global__ __launch_bounds__(256) void transpose_kernel(const float* __restrict__ src,
                                                        u16* __restrict__ dst,
                                                        int R, int C) {
    __shared__ float t[32][33];
    int lx = threadIdx.x & 31, ly = threadIdx.x >> 5;
    int c = blockIdx.x * 32 + lx;
#pragma unroll
    for (int i = 0; i < 32; i += 8)
        t[ly + i][lx] = src[(size_t)(blockIdx.y * 32 + ly + i) * C + c];
    __syncthreads();
    int rr = blockIdx.y * 32 + lx;
#pragma unroll
    for (int i = 0; i < 32; i += 8)
        dst[(size_t)(blockIdx.x * 32 + ly + i) * R + rr] = f2bf(t[lx][ly + i]);
}

// ---------------- 128x128 MFMA GEMM core (m97-style global_load_lds) -------
template <int K>
static __device__ __forceinline__ void gemm_core(const u16* __restrict__ A,
                                                 const u16* __restrict__ B,
                                                 int rowBase, int colBase,
                                                 u16* A_lds, u16* B_lds,
                                                 f32x4 acc[4][4]) {
    int tid = threadIdx.x;
    int lane = tid & 63;
    int l15 = lane & 15, q4 = lane >> 4;
    int w = tid >> 6;
    int wm = w >> 1, wn = w & 1;
#pragma unroll
    for (int mt = 0; mt < 4; mt++)
#pragma unroll
        for (int nt = 0; nt < 4; nt++) acc[mt][nt] = (f32x4){0.f, 0.f, 0.f, 0.f};

    char* Ab = (char*)A_lds;
    char* Bb = (char*)B_lds;

    for (int k0 = 0; k0 < K; k0 += 32) {
        __syncthreads();
#pragma unroll
        for (int i = 0; i < 2; i++) {
            int c = i * 256 + tid;
            int r = c >> 2;
            int piece = (c & 3) * 8;
            const u16* gA = A + (size_t)(rowBase + r) * K + k0 + piece;
            const u16* gB = B + (size_t)(colBase + r) * K + k0 + piece;
            unsigned ldsOff = (unsigned)(i * 4096 + w * 1024);  // wave-uniform
            __builtin_amdgcn_global_load_lds((gptr_t)gA, (lptr_t)(Ab + ldsOff), 16, 0, 0);
            __builtin_amdgcn_global_load_lds((gptr_t)gB, (lptr_t)(Bb + ldsOff), 16, 0, 0);
        }
        __syncthreads();
        bf16x8 a[4], b[4];
#pragma unroll
        for (int mt = 0; mt < 4; mt++)
            a[mt] = *(const bf16x8*)(A_lds + (wm * 64 + mt * 16 + l15) * 32 + q4 * 8);
#pragma unroll
        for (int nt = 0; nt < 4; nt++)
            b[nt] = *(const bf16x8*)(B_lds + (wn * 64 + nt * 16 + l15) * 32 + q4 * 8);
#pragma unroll
        for (int mt = 0; mt < 4; mt++)
#pragma unroll
            for (int nt = 0; nt < 4; nt++)
                acc[mt][nt] = mfma_bf16(a[mt], b[nt], acc[mt][nt]);
    }
}

// QKV GEMM: q gets softmax scale pre-folded; v stored transposed [bh][d][n]
__global__ __launch_bounds__(256) void gemm_qkv_kernel(const u16* __restrict__ xn,
                                                       const u16* __restrict__ wT,
                                                       u16* __restrict__ qb,
                                                       u16* __restrict__ kb,
                                                       u16* __restrict__ vbT) {
    __shared__ u16 A_lds[128 * 32];
    __shared__ u16 B_lds[128 * 32];
    f32x4 acc[4][4];
    gemm_core<1024>(xn, wT, blockIdx.x * 128, blockIdx.y * 128, A_lds, B_lds, acc);
    int lane = threadIdx.x & 63;
    int w = threadIdx.x >> 6;
    int wm = w >> 1, wn = w & 1;
    const float SC = 0.125f * 1.44269504f;  // scale * log2(e), folded into q
#pragma unroll
    for (int mt = 0; mt < 4; mt++) {
#pragma unroll
        for (int nt = 0; nt < 4; nt++) {
#pragma unroll
            for (int r = 0; r < 4; r++) {
                int m = blockIdx.x * 128 + wm * 64 + mt * 16 + (lane >> 4) * 4 + r;
                int n = blockIdx.y * 128 + wn * 64 + nt * 16 + (lane & 15);
                int piece = n >> 9;
                int c = n & 511;
                int h = c >> 6;
                int d = c & 63;
                int bi = m >> 12;
                int nn = m & 4095;
                int bh = bi * 8 + h;
                float av = acc[mt][nt][r];
                if (piece == 0)      qb[((size_t)(bh * SEQ + nn) << 6) + d] = f2bf(av * SC);
                else if (piece == 1) kb[((size_t)(bh * SEQ + nn) << 6) + d] = f2bf(av);
                else                 vbT[((size_t)(bh * 64 + d) << 12) + nn] = f2bf(av);
            }
        }
    }
}

// Out projection GEMM -> d_out fp32
__global__ __launch_bounds__(256) void gemm_out_kernel(const u16* __restrict__ aout,
                                                       const u16* __restrict__ wT,
                                                       float* __restrict__ out) {
    __shared__ u16 A_lds[128 * 32];
    __shared__ u16 B_lds[128 * 32];
    f32x4 acc[4][4];
    gemm_core<512>(aout, wT, blockIdx.x * 128, blockIdx.y * 128, A_lds, B_lds, acc);
    int lane = threadIdx.x & 63;
    int w = threadIdx.x >> 6;
    int wm = w >> 1, wn = w & 1;
#pragma unroll
    for (int mt = 0; mt < 4; mt++) {
#pragma unroll
        for (int nt = 0; nt < 4; nt++) {
#pragma unroll
            for (int r = 0; r < 4; r++) {
                int m = blockIdx.x * 128 + wm * 64 + mt * 16 + (lane >> 4) * 4 + r;
                int n = blockIdx.y * 128 + wn * 64 + nt * 16 + (lane & 15);
                out[(size_t)m * DIM + n] = acc[mt][nt][r];
            }
        }
    }
}

// ---------------- split-K causal flash attention (no-max softmax) ----------
// Block = (bh, qt, chunk ci); chunk covers kt in [ci*32, min(ci*32+31, qt)].
// Slot s in [0,96): qt<32 -> s=qt (ci=0); qt>=32 -> s=32+(qt-32)*2+ci.
// Partials: Onum bf16 [slot][64q][64d], l fp32 [slot][64q]; combine sums.
#define ASTR 72  // 64 + 8 pad

__global__ __launch_bounds__(256) void attn_partial_kernel(const u16* __restrict__ qb,
                                                           const u16* __restrict__ kb,
                                                           const u16* __restrict__ vbT,
                                                           u16* __restrict__ part,
                                                           float* __restrict__ lpart) {
    __shared__ u16 K_lds[64 * ASTR];
    __shared__ u16 VT_lds[64 * ASTR];
    __shared__ u16 QP_lds[64 * ASTR];  // Q tile, then per-wave P scratch

    int idx = NBH * NSLOT - 1 - blockIdx.x;  // big chunks dispatch first
    int bh = idx / NSLOT;
    int s  = idx - bh * NSLOT;
    int qt, ci;
    if (s < 32) { qt = s; ci = 0; }
    else        { int t = s - 32; qt = 32 + (t >> 1); ci = t & 1; }
    int kt0 = ci * 32;
    int kt1 = min(kt0 + 31, qt);

    int tid = threadIdx.x;
    int lane = tid & 63;
    int l15 = lane & 15, q4 = lane >> 4;
    int w = tid >> 6;

    const u16* Qp  = qb + ((size_t)bh * SEQ + qt * 64) * 64;
    const u16* Kp0 = kb + (size_t)bh * SEQ * 64;
    const u16* VTp = vbT + ((size_t)bh * 64) * SEQ;

#pragma unroll
    for (int i = 0; i < 2; i++) {
        int c = tid + 256 * i;
        int r = c >> 3;
        int kc = (c & 7) * 8;
        *(u16x8*)(QP_lds + r * ASTR + kc) = *(const u16x8*)(Qp + r * 64 + kc);
    }
    __syncthreads();
    bf16x8 aQ0 = *(const bf16x8*)(QP_lds + (w * 16 + l15) * ASTR + q4 * 8);
    bf16x8 aQ1 = *(const bf16x8*)(QP_lds + (w * 16 + l15) * ASTR + 32 + q4 * 8);
    __syncthreads();  // drain Q reads before P overwrites the region

    f32x4 Oacc[4];
    f32x4 l_acc = (f32x4){0.f, 0.f, 0.f, 0.f};
#pragma unroll
    for (int vt = 0; vt < 4; vt++) Oacc[vt] = (f32x4){0.f, 0.f, 0.f, 0.f};

    const __bf16 one_bf = (__bf16)1.0f;
    bf16x8 vones = {one_bf, one_bf, one_bf, one_bf, one_bf, one_bf, one_bf, one_bf};

    u16* Pw = QP_lds + w * 16 * ASTR;

    int c0 = tid, c1 = tid + 256;
    int r0 = c0 >> 3, kc0 = (c0 & 7) * 8;
    int r1 = c1 >> 3, kc1 = (c1 & 7) * 8;

    // prefetch first k-tile
    u16x8 krA0, krA1, vrA0, vrA1;
    {
        const u16* Kp = Kp0 + (size_t)kt0 * 64 * 64;
        krA0 = *(const u16x8*)(Kp + r0 * 64 + kc0);
        krA1 = *(const u16x8*)(Kp + r1 * 64 + kc1);
        vrA0 = *(const u16x8*)(VTp + (size_t)r0 * SEQ + kt0 * 64 + kc0);
        vrA1 = *(const u16x8*)(VTp + (size_t)r1 * SEQ + kt0 * 64 + kc1);
    }

    for (int kt = kt0; kt <= kt1; kt++) {
        __syncthreads();
        *(u16x8*)(K_lds + r0 * ASTR + kc0) = krA0;
        *(u16x8*)(K_lds + r1 * ASTR + kc1) = krA1;
        *(u16x8*)(VT_lds + r0 * ASTR + kc0) = vrA0;
        *(u16x8*)(VT_lds + r1 * ASTR + kc1) = vrA1;
        // issue next tile's loads; they stay in flight across the barrier
        int ktn = (kt < kt1) ? kt + 1 : kt1;
        const u16* Kpn = Kp0 + (size_t)ktn * 64 * 64;
        u16x8 krB0 = *(const u16x8*)(Kpn + r0 * 64 + kc0);
        u16x8 krB1 = *(const u16x8*)(Kpn + r1 * 64 + kc1);
        u16x8 vrB0 = *(const u16x8*)(VTp + (size_t)r0 * SEQ + ktn * 64 + kc0);
        u16x8 vrB1 = *(const u16x8*)(VTp + (size_t)r1 * SEQ + ktn * 64 + kc1);
        __syncthreads();

        f32x4 sv[4];
#pragma unroll
        for (int nt = 0; nt < 4; nt++) {
            bf16x8 b0 = *(const bf16x8*)(K_lds + (nt * 16 + l15) * ASTR + q4 * 8);
            bf16x8 b1 = *(const bf16x8*)(K_lds + (nt * 16 + l15) * ASTR + 32 + q4 * 8);
            f32x4 z = (f32x4){0.f, 0.f, 0.f, 0.f};
            z = mfma_bf16(aQ0, b0, z);
            z = mfma_bf16(aQ1, b1, z);
            sv[nt] = z;
        }

        if (kt != qt) {
#pragma unroll
            for (int nt = 0; nt < 4; nt++)
#pragma unroll
                for (int r = 0; r < 4; r++)
                    Pw[(q4 * 4 + r) * ASTR + nt * 16 + l15] =
                        cvt_bf16(__builtin_amdgcn_exp2f(sv[nt][r]));
        } else {
#pragma unroll
            for (int nt = 0; nt < 4; nt++)
#pragma unroll
                for (int r = 0; r < 4; r++) {
                    int kg = nt * 16 + l15;
                    int qg = w * 16 + q4 * 4 + r;
                    float pv = (kg <= qg) ? __builtin_amdgcn_exp2f(sv[nt][r]) : 0.f;
                    Pw[(q4 * 4 + r) * ASTR + nt * 16 + l15] = cvt_bf16(pv);
                }
        }

        bf16x8 aP0 = *(const bf16x8*)(Pw + l15 * ASTR + q4 * 8);
        bf16x8 aP1 = *(const bf16x8*)(Pw + l15 * ASTR + 32 + q4 * 8);
        l_acc = mfma_bf16(aP0, vones, l_acc);   // denominator via ones-column MFMA
        l_acc = mfma_bf16(aP1, vones, l_acc);
#pragma unroll
        for (int vt = 0; vt < 4; vt++) {
            bf16x8 bV0 = *(const bf16x8*)(VT_lds + (vt * 16 + l15) * ASTR + q4 * 8);
            bf16x8 bV1 = *(const bf16x8*)(VT_lds + (vt * 16 + l15) * ASTR + 32 + q4 * 8);
            Oacc[vt] = mfma_bf16(aP0, bV0, Oacc[vt]);
            Oacc[vt] = mfma_bf16(aP1, bV1, Oacc[vt]);
        }

        krA0 = krB0; krA1 = krB1; vrA0 = vrB0; vrA1 = vrB1;
    }

    // write partials: Onum (bf16) + l (fp32); slot == idx
    u16* po = part + (size_t)idx * 4096;
#pragma unroll
    for (int vt = 0; vt < 4; vt++)
#pragma unroll
        for (int r = 0; r < 4; r++) {
            int q = w * 16 + q4 * 4 + r;
            int d = vt * 16 + l15;
            po[q * 64 + d] = f2bf(Oacc[vt][r]);
        }
    if (l15 == 0) {
#pragma unroll
        for (int r = 0; r < 4; r++)
            lpart[(size_t)idx * 64 + w * 16 + q4 * 4 + r] = l_acc[r];
    }
}

// combine partials -> aout bf16 [8192][512]
__global__ __launch_bounds__(256) void attn_combine_kernel(const u16* __restrict__ part,
                                                           const float* __restrict__ lpart,
                                                           u16* __restrict__ aout) {
    int bid = blockIdx.x;          // 16*64
    int bh = bid >> 6;
    int qt = bid & 63;
    int nc = 1 + (qt >> 5);
    int sb = bh * NSLOT + (qt < 32 ? qt : 32 + (qt - 32) * 2);

    int t = threadIdx.x;
    int q = t >> 2;
    int dg = (t & 3) * 16;

    float acc[16];
#pragma unroll
    for (int j = 0; j < 16; j++) acc[j] = 0.f;
    float ll = 0.f;
    for (int ci = 0; ci < nc; ci++) {
        const u16* pp = part + (size_t)(sb + ci) * 4096 + q * 64 + dg;
        u16x8 v0 = *(const u16x8*)pp;
        u16x8 v1 = *(const u16x8*)(pp + 8);
#pragma unroll
        for (int j = 0; j < 8; j++) { acc[j] += bf2f(v0[j]); acc[8 + j] += bf2f(v1[j]); }
        ll += lpart[(size_t)(sb + ci) * 64 + q];
    }
    float inv = 1.f / (ll + 1e-10f);
    int b = bh >> 3, h = bh & 7;
    size_t row = (size_t)(b * SEQ + qt * 64 + q);
    u16 o[16];
#pragma unroll
    for (int j = 0; j < 16; j++) o[j] = f2bf(acc[j] * inv);
    u16* dst = aout + row * 512 + h * 64 + dg;
    *(u16x8*)dst = *(u16x8*)o;
    *(u16x8*)(dst + 8) = *(u16x8*)(o + 8);
}

extern "C" void kernel_launch(void* const* d_in, const int* in_sizes, int n_in,
                              void* d_out, int out_size, void* d_ws, size_t ws_size,
                              hipStream_t stream) {
    const float* x    = (const float*)d_in[0];
    const float* g    = (const float*)d_in[1];
    const float* bta  = (const float*)d_in[2];
    const float* wqkv = (const float*)d_in[3];
    const float* wout = (const float*)d_in[4];
    float* out = (float*)d_out;

    char* ws = (char*)d_ws;
    size_t off = 0;
    auto alloc = [&](size_t bytes) {
        void* p = ws + off;
        off += (bytes + 255) & ~(size_t)255;
        return p;
    };
    // Footprint kept <= 46.1 MB (round-4's 54.6 MB is known-good; round-5's
    // 76 MB overran d_ws and corrupted neighboring allocations during timing).
    u16* xn    = (u16*)alloc((size_t)NTOK * DIM * 2);       // 16.78 MB; dead after gemm_qkv
    u16* wqkvT = (u16*)alloc((size_t)1536 * 1024 * 2);      //  3.15 MB
    u16* woutT = (u16*)alloc((size_t)1024 * 512 * 2);       //  1.05 MB
    u16* qb    = (u16*)alloc((size_t)NBH * SEQ * 64 * 2);   //  8.39 MB; dead after attn_partial
    u16* kb    = (u16*)alloc((size_t)NBH * SEQ * 64 * 2);   //  8.39 MB
    u16* vbT   = (u16*)alloc((size_t)NBH * SEQ * 64 * 2);   //  8.39 MB
    // Aliases (lifetimes disjoint by stream order, valid on every replay):
    u16* part  = xn;                                        // 12.58 MB into xn region
    float* lpart = (float*)(xn + (size_t)NBH * NSLOT * 4096); // +0.39 MB, still < xn's 16.78 MB
    u16* aout  = qb;                                        // combine writes after attn_partial reads qb

    ln_kernel<<<NTOK, 256, 0, stream>>>(x, g, bta, xn);
    transpose_kernel<<<dim3(1536 / 32, 1024 / 32), 256, 0, stream>>>(wqkv, wqkvT, 1024, 1536);
    transpose_kernel<<<dim3(1024 / 32, 512 / 32), 256, 0, stream>>>(wout, woutT, 512, 1024);
    gemm_qkv_kernel<<<dim3(64, 12), 256, 0, stream>>>(xn, wqkvT, qb, kb, vbT);
    attn_partial_kernel<<<NBH * NSLOT, 256, 0, stream>>>(qb, kb, vbT, part, lpart);
    attn_combine_kernel<<<NBH * 64, 256, 0, stream>>>(part, lpart, aout);
    gemm_out_kernel<<<dim3(64, 8), 256, 0, stream>>>(aout, woutT, out);
}